// Round 5
// baseline (189.940 us; speedup 1.0000x reference)
//
#include <hip/hip_runtime.h>

#define EPSV 1e-5f

// Workspace layout (floats):
//   kbuf @ 0     : [b][g][c][l]  8*4*8*49 = 12544
//   W    @ 12544 : [b][g][o<74][c<8]      = 18944   (W = proj_w @ k^T)
//   wq2  @ 31488 : [i][o] 32*32 (BN+scale folded)    = 1024
//   q0   @ 32512 : [o] 32  (folded BN bias * 0.25)   = 32
//   dyT  @ 32544 : [i][o] 64*64                       = 4096
#define OFF_W    12544
#define OFF_WQ2  31488
#define OFF_Q0   32512
#define OFF_DYT  32544

typedef float f4u __attribute__((ext_vector_type(4), aligned(4)));
typedef float f4a __attribute__((ext_vector_type(4), aligned(16)));

// ---------------------------------------------------------------------------
// Merged: blocks 0..55 = pool kctx->7x7 + wk conv + BN (kbuf [b][g][c][l]);
// blocks 56..63 = weight prep (wq2/q0 folded BN, dyT transpose).
// ---------------------------------------------------------------------------
__global__ __launch_bounds__(256) void pool_prep_kernel(
    const float* __restrict__ x,
    const float* __restrict__ wk_w, const float* __restrict__ wk_g,
    const float* __restrict__ wk_b, const float* __restrict__ wk_m,
    const float* __restrict__ wk_v,
    const float* __restrict__ wq_w, const float* __restrict__ wq_g,
    const float* __restrict__ wq_b, const float* __restrict__ wq_m,
    const float* __restrict__ wq_v,
    const float* __restrict__ dy_w,
    float* __restrict__ ws)
{
  __shared__ float s_tmp[32 * 64];
  __shared__ float s_kp[32 * 7];
  const int tid = threadIdx.x;

  if (blockIdx.x >= 56) {
    const int t = (blockIdx.x - 56) * 256 + tid;  // 0..2047
    for (int idx = t; idx < 1056; idx += 2048) {
      if (idx < 1024) {
        const int i = idx >> 5, o = idx & 31;
        const float s = wq_g[o] * rsqrtf(wq_v[o] + EPSV);
        ws[OFF_WQ2 + idx] = 0.25f * s * wq_w[o * 32 + i];
      } else {
        const int o = idx - 1024;
        const float s = wq_g[o] * rsqrtf(wq_v[o] + EPSV);
        ws[OFF_Q0 + o] = 0.25f * (wq_b[o] - wq_m[o] * s);
      }
    }
    for (int idx = t; idx < 4096; idx += 2048) {
      const int i = idx >> 6, o = idx & 63;
      ws[OFF_DYT + idx] = dy_w[o * 64 + i];
    }
    return;
  }

  const int b = blockIdx.x / 7;
  const int p = blockIdx.x % 7;
  const int sh = (p * 64) / 7, eh = ((p + 1) * 64 + 6) / 7;
  const float invH = 1.0f / (float)(eh - sh);
  for (int idx = tid; idx < 2048; idx += 256) {
    const int c = idx >> 6, ww = idx & 63;
    const float* xp = x + ((size_t)(b * 64 + 32 + c)) * 4096 + ww;
    float s = 0.f;
    for (int hh = sh; hh < eh; ++hh) s += xp[hh * 64];
    s_tmp[idx] = s * invH;
  }
  __syncthreads();
  if (tid < 224) {
    const int c = tid / 7, q = tid % 7;
    const int sw = (q * 64) / 7, ew = ((q + 1) * 64 + 6) / 7;
    float s = 0.f;
    for (int ww = sw; ww < ew; ++ww) s += s_tmp[c * 64 + ww];
    s_kp[c * 7 + q] = s / (float)(ew - sw);
  }
  __syncthreads();
  if (tid < 224) {
    const int o = tid / 7, q = tid % 7;
    float s = 0.f;
#pragma unroll
    for (int i = 0; i < 32; i++) s += wk_w[o * 32 + i] * s_kp[i * 7 + q];
    const float sc = wk_g[o] * rsqrtf(wk_v[o] + EPSV);
    const int g = o >> 3, c = o & 7, l = p * 7 + q;
    ws[(((size_t)b * 4 + g) * 8 + c) * 49 + l] = (s - wk_m[o]) * sc + wk_b[o];
  }
}

// ---------------------------------------------------------------------------
// W[bg][o][c] = sum_l proj_w[o][l] * k[bg][c][l].
// ---------------------------------------------------------------------------
__global__ __launch_bounds__(256) void fold_w_kernel(
    const float* __restrict__ proj_w, const float* __restrict__ ws_in,
    float* __restrict__ Wout)
{
  const int bg = blockIdx.x;
  const int tid = threadIdx.x;
  __shared__ float s_k[392];
  for (int i = tid; i < 392; i += 256) s_k[i] = ws_in[(size_t)bg * 392 + i];
  __syncthreads();
  for (int idx = tid; idx < 592; idx += 256) {
    const int o = idx >> 3, c = idx & 7;
    float s = 0.f;
#pragma unroll
    for (int l = 0; l < 49; l++) s += proj_w[o * 49 + l] * s_k[c * 49 + l];
    Wout[(size_t)bg * 592 + idx] = s;
  }
}

// ---------------------------------------------------------------------------
// Fused main. Block = 512 = 2 branches x 4 heads x 64 cols, one row.
// s_x: q-input row staged in LDS. s_val transposed [w][ch] pad 68 so the
// final conv reads ds_read_b128. Softmax without max-subtraction (exact).
// ---------------------------------------------------------------------------
__global__ __launch_bounds__(512, 3) void contmix_main(
    const float* __restrict__ x,
    const float* __restrict__ proj_b,
    const float* __restrict__ rpb1, const float* __restrict__ rpb2,
    const float* __restrict__ dy_g, const float* __restrict__ dy_b,
    const float* __restrict__ dy_m, const float* __restrict__ dy_v,
    const float* __restrict__ ws,
    float* __restrict__ out)
{
  __shared__ __align__(16) float s_val[64 * 68];  // [w][ch], pad 68
  __shared__ float s_x[32 * 64];                  // [c][w] q-input row
  __shared__ float s_rpb1[324];
  __shared__ float s_rpb2[676];

  const int b = blockIdx.x >> 6;
  const int h = blockIdx.x & 63;
  const int tid = threadIdx.x;
  const int w = tid & 63;
  const int bru = __builtin_amdgcn_readfirstlane(tid >> 8);
  const int gu  = __builtin_amdgcn_readfirstlane((tid >> 6) & 3);

  const float* xb = x + (size_t)b * 64 * 4096;

  {
    const float* xr = xb + h * 64;
    for (int idx = tid; idx < 2048; idx += 512)
      s_x[idx] = xr[(size_t)(idx >> 6) * 4096 + (idx & 63)];
  }
  for (int i = tid; i < 324; i += 512) s_rpb1[i] = rpb1[i];
  for (int i = tid; i < 676; i += 512) s_rpb2[i] = rpb2[i];
  __syncthreads();

  // ---- q8 from LDS (BN+scale pre-folded into wq2/q0) ----
  float q8[8];
  {
    const float* q0 = ws + OFF_Q0 + gu * 8;
#pragma unroll
    for (int o = 0; o < 8; o++) q8[o] = q0[o];
    const float* wq2 = ws + OFF_WQ2 + gu * 8;
#pragma unroll
    for (int i = 0; i < 32; i++) {
      const float xv = s_x[i * 64 + w];
#pragma unroll
      for (int o = 0; o < 8; o++) q8[o] += wq2[i * 32 + o] * xv;
    }
  }

  const float* Wr = ws + OFF_W + (size_t)(b * 4 + gu) * 592;  // uniform
  const int ph = 63 - h, pw = 63 - w;
  float* svrow = s_val + w * 68;

  if (bru == 0) {
    // ===== attn1 (5x5) =====
    const int bih5 = ph - min(max(ph - 2, 0), 59);
    const int biw5 = pw - min(max(pw - 2, 0), 59);
    const int si5 = min(max(h - 2, 0), 59), sj5 = min(max(w - 2, 0), 59);
    float l1[25];
#pragma unroll
    for (int o = 0; o < 25; o++) {
      const float* wo = Wr + o * 8;
      float s = proj_b[o];
#pragma unroll
      for (int c = 0; c < 8; c++) s += wo[c] * q8[c];
      l1[o] = s;
    }
    const float* rp1 = s_rpb1 + gu * 81 + bih5 * 9 + biw5;
#pragma unroll
    for (int ki = 0; ki < 5; ki++)
#pragma unroll
      for (int kj = 0; kj < 5; kj++) l1[ki * 5 + kj] += rp1[ki * 9 + kj];

    float p0 = 0.f, p1 = 0.f, p2 = 0.f, p3 = 0.f;
#pragma unroll
    for (int o = 0; o < 25; o++) {
      const float e = __expf(l1[o]);
      l1[o] = e;
      if ((o & 3) == 0) p0 += e;
      else if ((o & 3) == 1) p1 += e;
      else if ((o & 3) == 2) p2 += e;
      else p3 += e;
    }
    const float inv = 1.f / ((p0 + p1) + (p2 + p3));

    float acc[8];
#pragma unroll
    for (int c = 0; c < 8; c++) acc[c] = 0.f;
    const float* vb = xb + gu * 8 * 4096;
#pragma unroll
    for (int i = 0; i < 5; i++) {
      const float a0 = l1[i * 5 + 0], a1 = l1[i * 5 + 1], a2 = l1[i * 5 + 2];
      const float a3 = l1[i * 5 + 3], a4 = l1[i * 5 + 4];
      const float* vr0 = vb + (si5 + i) * 64 + sj5;
#pragma unroll
      for (int c = 0; c < 8; c++) {
        const float* vr = vr0 + c * 4096;
        const f4u f = *(const f4u*)vr;
        const float v4 = vr[4];
        acc[c] += a0 * f.x + a1 * f.y + a2 * f.z + a3 * f.w + a4 * v4;
      }
    }
    f4a v0, v1;
    v0.x = acc[0] * inv; v0.y = acc[1] * inv; v0.z = acc[2] * inv; v0.w = acc[3] * inv;
    v1.x = acc[4] * inv; v1.y = acc[5] * inv; v1.z = acc[6] * inv; v1.w = acc[7] * inv;
    *(f4a*)(svrow + gu * 8) = v0;
    *(f4a*)(svrow + gu * 8 + 4) = v1;
  } else {
    // ===== attn2 (7x7) =====
    const int bih7 = ph - min(max(ph - 3, 0), 57);
    const int biw7 = pw - min(max(pw - 3, 0), 57);
    const int si7 = min(max(h - 3, 0), 57), sj7 = min(max(w - 3, 0), 57);
    float l2[49];
#pragma unroll
    for (int o = 0; o < 49; o++) {
      const float* wo = Wr + (25 + o) * 8;
      float s = proj_b[25 + o];
#pragma unroll
      for (int c = 0; c < 8; c++) s += wo[c] * q8[c];
      l2[o] = s;
    }
    const float* rp2 = s_rpb2 + gu * 169 + bih7 * 13 + biw7;
#pragma unroll
    for (int ki = 0; ki < 7; ki++)
#pragma unroll
      for (int kj = 0; kj < 7; kj++) l2[ki * 7 + kj] += rp2[ki * 13 + kj];

    float p0 = 0.f, p1 = 0.f, p2 = 0.f, p3 = 0.f;
#pragma unroll
    for (int o = 0; o < 49; o++) {
      const float e = __expf(l2[o]);
      l2[o] = e;
      if ((o & 3) == 0) p0 += e;
      else if ((o & 3) == 1) p1 += e;
      else if ((o & 3) == 2) p2 += e;
      else p3 += e;
    }
    const float inv = 1.f / ((p0 + p1) + (p2 + p3));

    float acc[8];
#pragma unroll
    for (int c = 0; c < 8; c++) acc[c] = 0.f;
    const float* vb = xb + (32 + gu * 8) * 4096;
#pragma unroll
    for (int i = 0; i < 7; i++) {
      const float a0 = l2[i * 7 + 0], a1 = l2[i * 7 + 1], a2 = l2[i * 7 + 2];
      const float a3 = l2[i * 7 + 3], a4 = l2[i * 7 + 4], a5 = l2[i * 7 + 5];
      const float a6 = l2[i * 7 + 6];
      const float* vr0 = vb + (si7 + i) * 64 + sj7;
#pragma unroll
      for (int c = 0; c < 8; c++) {
        const float* vr = vr0 + c * 4096;
        const f4u fa = *(const f4u*)vr;
        const f4u fb = *(const f4u*)(vr + 3);
        acc[c] += a0 * fa.x + a1 * fa.y + a2 * fa.z + a3 * fa.w +
                  a4 * fb.y + a5 * fb.z + a6 * fb.w;
      }
    }
    f4a v0, v1;
    v0.x = acc[0] * inv; v0.y = acc[1] * inv; v0.z = acc[2] * inv; v0.w = acc[3] * inv;
    v1.x = acc[4] * inv; v1.y = acc[5] * inv; v1.z = acc[6] * inv; v1.w = acc[7] * inv;
    *(f4a*)(svrow + 32 + gu * 8) = v0;
    *(f4a*)(svrow + 32 + gu * 8 + 4) = v1;
  }

  __syncthreads();

  // ===== fused final conv1x1 (64->64) + BN; s_val read as b128 =====
  {
    const int ogu = __builtin_amdgcn_readfirstlane(tid >> 6);  // 0..7
    float facc[8];
#pragma unroll
    for (int oo = 0; oo < 8; oo++) facc[oo] = 0.f;
    const float* dyt = ws + OFF_DYT + ogu * 8;
    const f4a* sv = (const f4a*)svrow;
#pragma unroll
    for (int k = 0; k < 16; k++) {
      const f4a v4 = sv[k];
#pragma unroll
      for (int j = 0; j < 4; j++) {
        const int i = 4 * k + j;
        const float v = (j == 0) ? v4.x : (j == 1) ? v4.y : (j == 2) ? v4.z : v4.w;
#pragma unroll
        for (int oo = 0; oo < 8; oo++) facc[oo] += dyt[i * 64 + oo] * v;
      }
    }
#pragma unroll
    for (int oo = 0; oo < 8; oo++) {
      const int oc = ogu * 8 + oo;
      const float sc = dy_g[oc] * rsqrtf(dy_v[oc] + EPSV);
      out[((size_t)(b * 64 + oc)) * 4096 + h * 64 + w] =
          (facc[oo] - dy_m[oc]) * sc + dy_b[oc];
    }
  }
}

// ---------------------------------------------------------------------------
extern "C" void kernel_launch(void* const* d_in, const int* in_sizes, int n_in,
                              void* d_out, int out_size, void* d_ws, size_t ws_size,
                              hipStream_t stream)
{
  const float* x      = (const float*)d_in[0];
  const float* wq_w   = (const float*)d_in[1];
  const float* wq_g   = (const float*)d_in[2];
  const float* wq_b   = (const float*)d_in[3];
  const float* wq_m   = (const float*)d_in[4];
  const float* wq_v   = (const float*)d_in[5];
  const float* wk_w   = (const float*)d_in[6];
  const float* wk_g   = (const float*)d_in[7];
  const float* wk_b   = (const float*)d_in[8];
  const float* wk_m   = (const float*)d_in[9];
  const float* wk_v   = (const float*)d_in[10];
  const float* proj_w = (const float*)d_in[11];
  const float* proj_b = (const float*)d_in[12];
  const float* rpb1   = (const float*)d_in[13];
  const float* rpb2   = (const float*)d_in[14];
  const float* dy_w   = (const float*)d_in[15];
  const float* dy_g   = (const float*)d_in[16];
  const float* dy_b   = (const float*)d_in[17];
  const float* dy_m   = (const float*)d_in[18];
  const float* dy_v   = (const float*)d_in[19];

  float* ws = (float*)d_ws;

  pool_prep_kernel<<<64, 256, 0, stream>>>(x, wk_w, wk_g, wk_b, wk_m, wk_v,
                                           wq_w, wq_g, wq_b, wq_m, wq_v,
                                           dy_w, ws);
  fold_w_kernel<<<32, 256, 0, stream>>>(proj_w, ws, ws + OFF_W);
  contmix_main<<<512, 512, 0, stream>>>(x, proj_b, rpb1, rpb2,
                                        dy_g, dy_b, dy_m, dy_v,
                                        ws, (float*)d_out);
}

// Round 6
// 181.158 us; speedup vs baseline: 1.0485x; 1.0485x over previous
//
#include <hip/hip_runtime.h>

#define EPSV 1e-5f

// Workspace layout (floats):
//   kbuf @ 0     : [b][g][c][l]  8*4*8*49 = 12544
//   W    @ 12544 : [b][g][o<74][c<8]      = 18944   (W = proj_w @ k^T)
//   wq2  @ 31488 : [i][o] 32*32 (BN+scale folded)    = 1024
//   q0   @ 32512 : [o] 32  (folded BN bias * 0.25)   = 32
//   dyT  @ 32544 : [i][o] 64*64                       = 4096
#define OFF_W    12544
#define OFF_WQ2  31488
#define OFF_Q0   32512
#define OFF_DYT  32544

typedef float f4u __attribute__((ext_vector_type(4), aligned(4)));
typedef float f4a __attribute__((ext_vector_type(4), aligned(16)));

// ---------------------------------------------------------------------------
// Merged: blocks 0..55 = pool kctx->7x7 + wk conv + BN (kbuf [b][g][c][l]);
// blocks 56..63 = weight prep (wq2/q0 folded BN, dyT transpose).
// ---------------------------------------------------------------------------
__global__ __launch_bounds__(256) void pool_prep_kernel(
    const float* __restrict__ x,
    const float* __restrict__ wk_w, const float* __restrict__ wk_g,
    const float* __restrict__ wk_b, const float* __restrict__ wk_m,
    const float* __restrict__ wk_v,
    const float* __restrict__ wq_w, const float* __restrict__ wq_g,
    const float* __restrict__ wq_b, const float* __restrict__ wq_m,
    const float* __restrict__ wq_v,
    const float* __restrict__ dy_w,
    float* __restrict__ ws)
{
  __shared__ float s_tmp[32 * 64];
  __shared__ float s_kp[32 * 7];
  const int tid = threadIdx.x;

  if (blockIdx.x >= 56) {
    const int t = (blockIdx.x - 56) * 256 + tid;  // 0..2047
    for (int idx = t; idx < 1056; idx += 2048) {
      if (idx < 1024) {
        const int i = idx >> 5, o = idx & 31;
        const float s = wq_g[o] * rsqrtf(wq_v[o] + EPSV);
        ws[OFF_WQ2 + idx] = 0.25f * s * wq_w[o * 32 + i];
      } else {
        const int o = idx - 1024;
        const float s = wq_g[o] * rsqrtf(wq_v[o] + EPSV);
        ws[OFF_Q0 + o] = 0.25f * (wq_b[o] - wq_m[o] * s);
      }
    }
    for (int idx = t; idx < 4096; idx += 2048) {
      const int i = idx >> 6, o = idx & 63;
      ws[OFF_DYT + idx] = dy_w[o * 64 + i];
    }
    return;
  }

  const int b = blockIdx.x / 7;
  const int p = blockIdx.x % 7;
  const int sh = (p * 64) / 7, eh = ((p + 1) * 64 + 6) / 7;
  const float invH = 1.0f / (float)(eh - sh);
  for (int idx = tid; idx < 2048; idx += 256) {
    const int c = idx >> 6, ww = idx & 63;
    const float* xp = x + ((size_t)(b * 64 + 32 + c)) * 4096 + ww;
    float s = 0.f;
    for (int hh = sh; hh < eh; ++hh) s += xp[hh * 64];
    s_tmp[idx] = s * invH;
  }
  __syncthreads();
  if (tid < 224) {
    const int c = tid / 7, q = tid % 7;
    const int sw = (q * 64) / 7, ew = ((q + 1) * 64 + 6) / 7;
    float s = 0.f;
    for (int ww = sw; ww < ew; ++ww) s += s_tmp[c * 64 + ww];
    s_kp[c * 7 + q] = s / (float)(ew - sw);
  }
  __syncthreads();
  if (tid < 224) {
    const int o = tid / 7, q = tid % 7;
    float s = 0.f;
#pragma unroll
    for (int i = 0; i < 32; i++) s += wk_w[o * 32 + i] * s_kp[i * 7 + q];
    const float sc = wk_g[o] * rsqrtf(wk_v[o] + EPSV);
    const int g = o >> 3, c = o & 7, l = p * 7 + q;
    ws[(((size_t)b * 4 + g) * 8 + c) * 49 + l] = (s - wk_m[o]) * sc + wk_b[o];
  }
}

// ---------------------------------------------------------------------------
// W[bg][o][c] = sum_l proj_w[o][l] * k[bg][c][l].
// ---------------------------------------------------------------------------
__global__ __launch_bounds__(256) void fold_w_kernel(
    const float* __restrict__ proj_w, const float* __restrict__ ws_in,
    float* __restrict__ Wout)
{
  const int bg = blockIdx.x;
  const int tid = threadIdx.x;
  __shared__ float s_k[392];
  for (int i = tid; i < 392; i += 256) s_k[i] = ws_in[(size_t)bg * 392 + i];
  __syncthreads();
  for (int idx = tid; idx < 592; idx += 256) {
    const int o = idx >> 3, c = idx & 7;
    float s = 0.f;
#pragma unroll
    for (int l = 0; l < 49; l++) s += proj_w[o * 49 + l] * s_k[c * 49 + l];
    Wout[(size_t)bg * 592 + idx] = s;
  }
}

// ---------------------------------------------------------------------------
// Fused main. Block = 512 = 2 branches x 4 heads x 64 cols, one row.
// amdgpu_waves_per_eu(4,4) pins VGPR budget to 128 (grid is 2 blocks/CU =
// 4 waves/EU anyway) so the allocator stops spilling l1/l2 to scratch.
// ---------------------------------------------------------------------------
__global__ __launch_bounds__(512)
__attribute__((amdgpu_waves_per_eu(4, 4)))
void contmix_main(
    const float* __restrict__ x,
    const float* __restrict__ proj_b,
    const float* __restrict__ rpb1, const float* __restrict__ rpb2,
    const float* __restrict__ dy_g, const float* __restrict__ dy_b,
    const float* __restrict__ dy_m, const float* __restrict__ dy_v,
    const float* __restrict__ ws,
    float* __restrict__ out)
{
  __shared__ __align__(16) float s_val[64 * 68];  // [w][ch], pad 68
  __shared__ float s_x[32 * 64];                  // [c][w] q-input row
  __shared__ float s_rpb1[324];
  __shared__ float s_rpb2[676];

  const int b = blockIdx.x >> 6;
  const int h = blockIdx.x & 63;
  const int tid = threadIdx.x;
  const int w = tid & 63;
  const int bru = __builtin_amdgcn_readfirstlane(tid >> 8);
  const int gu  = __builtin_amdgcn_readfirstlane((tid >> 6) & 3);

  const float* xb = x + (size_t)b * 64 * 4096;

  {
    const float* xr = xb + h * 64;
    for (int idx = tid; idx < 2048; idx += 512)
      s_x[idx] = xr[(size_t)(idx >> 6) * 4096 + (idx & 63)];
  }
  for (int i = tid; i < 324; i += 512) s_rpb1[i] = rpb1[i];
  for (int i = tid; i < 676; i += 512) s_rpb2[i] = rpb2[i];
  __syncthreads();

  // ---- q8 from LDS (BN+scale pre-folded into wq2/q0) ----
  float q8[8];
  {
    const float* q0 = ws + OFF_Q0 + gu * 8;
#pragma unroll
    for (int o = 0; o < 8; o++) q8[o] = q0[o];
    const float* wq2 = ws + OFF_WQ2 + gu * 8;
#pragma unroll
    for (int i = 0; i < 32; i++) {
      const float xv = s_x[i * 64 + w];
#pragma unroll
      for (int o = 0; o < 8; o++) q8[o] += wq2[i * 32 + o] * xv;
    }
  }

  const float* Wr = ws + OFF_W + (size_t)(b * 4 + gu) * 592;  // uniform
  const int ph = 63 - h, pw = 63 - w;
  float* svrow = s_val + w * 68;

  if (bru == 0) {
    // ===== attn1 (5x5) =====
    const int bih5 = ph - min(max(ph - 2, 0), 59);
    const int biw5 = pw - min(max(pw - 2, 0), 59);
    const int si5 = min(max(h - 2, 0), 59), sj5 = min(max(w - 2, 0), 59);
    float l1[25];
#pragma unroll
    for (int o = 0; o < 25; o++) {
      const float* wo = Wr + o * 8;
      float s = proj_b[o];
#pragma unroll
      for (int c = 0; c < 8; c++) s += wo[c] * q8[c];
      l1[o] = s;
    }
    const float* rp1 = s_rpb1 + gu * 81 + bih5 * 9 + biw5;
#pragma unroll
    for (int ki = 0; ki < 5; ki++)
#pragma unroll
      for (int kj = 0; kj < 5; kj++) l1[ki * 5 + kj] += rp1[ki * 9 + kj];

    float p0 = 0.f, p1 = 0.f, p2 = 0.f, p3 = 0.f;
#pragma unroll
    for (int o = 0; o < 25; o++) {
      const float e = __expf(l1[o]);
      l1[o] = e;
      if ((o & 3) == 0) p0 += e;
      else if ((o & 3) == 1) p1 += e;
      else if ((o & 3) == 2) p2 += e;
      else p3 += e;
    }
    const float inv = 1.f / ((p0 + p1) + (p2 + p3));

    float acc[8];
#pragma unroll
    for (int c = 0; c < 8; c++) acc[c] = 0.f;
    const float* vb = xb + gu * 8 * 4096;
#pragma unroll
    for (int i = 0; i < 5; i++) {
      const float a0 = l1[i * 5 + 0], a1 = l1[i * 5 + 1], a2 = l1[i * 5 + 2];
      const float a3 = l1[i * 5 + 3], a4 = l1[i * 5 + 4];
      const float* vr0 = vb + (si5 + i) * 64 + sj5;
#pragma unroll
      for (int c = 0; c < 8; c++) {
        const float* vr = vr0 + c * 4096;
        const f4u f = *(const f4u*)vr;
        const float v4 = vr[4];
        acc[c] += a0 * f.x + a1 * f.y + a2 * f.z + a3 * f.w + a4 * v4;
      }
    }
    f4a v0, v1;
    v0.x = acc[0] * inv; v0.y = acc[1] * inv; v0.z = acc[2] * inv; v0.w = acc[3] * inv;
    v1.x = acc[4] * inv; v1.y = acc[5] * inv; v1.z = acc[6] * inv; v1.w = acc[7] * inv;
    *(f4a*)(svrow + gu * 8) = v0;
    *(f4a*)(svrow + gu * 8 + 4) = v1;
  } else {
    // ===== attn2 (7x7) =====
    const int bih7 = ph - min(max(ph - 3, 0), 57);
    const int biw7 = pw - min(max(pw - 3, 0), 57);
    const int si7 = min(max(h - 3, 0), 57), sj7 = min(max(w - 3, 0), 57);
    float l2[49];
#pragma unroll
    for (int o = 0; o < 49; o++) {
      const float* wo = Wr + (25 + o) * 8;
      float s = proj_b[25 + o];
#pragma unroll
      for (int c = 0; c < 8; c++) s += wo[c] * q8[c];
      l2[o] = s;
    }
    const float* rp2 = s_rpb2 + gu * 169 + bih7 * 13 + biw7;
#pragma unroll
    for (int ki = 0; ki < 7; ki++)
#pragma unroll
      for (int kj = 0; kj < 7; kj++) l2[ki * 7 + kj] += rp2[ki * 13 + kj];

    float p0 = 0.f, p1 = 0.f, p2 = 0.f, p3 = 0.f;
#pragma unroll
    for (int o = 0; o < 49; o++) {
      const float e = __expf(l2[o]);
      l2[o] = e;
      if ((o & 3) == 0) p0 += e;
      else if ((o & 3) == 1) p1 += e;
      else if ((o & 3) == 2) p2 += e;
      else p3 += e;
    }
    const float inv = 1.f / ((p0 + p1) + (p2 + p3));

    float acc[8];
#pragma unroll
    for (int c = 0; c < 8; c++) acc[c] = 0.f;
    const float* vb = xb + (32 + gu * 8) * 4096;
#pragma unroll
    for (int i = 0; i < 7; i++) {
      const float a0 = l2[i * 7 + 0], a1 = l2[i * 7 + 1], a2 = l2[i * 7 + 2];
      const float a3 = l2[i * 7 + 3], a4 = l2[i * 7 + 4], a5 = l2[i * 7 + 5];
      const float a6 = l2[i * 7 + 6];
      const float* vr0 = vb + (si7 + i) * 64 + sj7;
#pragma unroll
      for (int c = 0; c < 8; c++) {
        const float* vr = vr0 + c * 4096;
        const f4u fa = *(const f4u*)vr;
        const f4u fb = *(const f4u*)(vr + 3);
        acc[c] += a0 * fa.x + a1 * fa.y + a2 * fa.z + a3 * fa.w +
                  a4 * fb.y + a5 * fb.z + a6 * fb.w;
      }
    }
    f4a v0, v1;
    v0.x = acc[0] * inv; v0.y = acc[1] * inv; v0.z = acc[2] * inv; v0.w = acc[3] * inv;
    v1.x = acc[4] * inv; v1.y = acc[5] * inv; v1.z = acc[6] * inv; v1.w = acc[7] * inv;
    *(f4a*)(svrow + 32 + gu * 8) = v0;
    *(f4a*)(svrow + 32 + gu * 8 + 4) = v1;
  }

  __syncthreads();

  // ===== fused final conv1x1 (64->64) + BN; s_val read as b128 =====
  // unroll 4 (not 16) so only 4 ds_read_b128 results are live at once.
  {
    const int ogu = __builtin_amdgcn_readfirstlane(tid >> 6);  // 0..7
    float facc[8];
#pragma unroll
    for (int oo = 0; oo < 8; oo++) facc[oo] = 0.f;
    const float* dyt = ws + OFF_DYT + ogu * 8;
    const f4a* sv = (const f4a*)svrow;
#pragma unroll 4
    for (int k = 0; k < 16; k++) {
      const f4a v4 = sv[k];
#pragma unroll
      for (int j = 0; j < 4; j++) {
        const int i = 4 * k + j;
        const float v = (j == 0) ? v4.x : (j == 1) ? v4.y : (j == 2) ? v4.z : v4.w;
#pragma unroll
        for (int oo = 0; oo < 8; oo++) facc[oo] += dyt[i * 64 + oo] * v;
      }
    }
#pragma unroll
    for (int oo = 0; oo < 8; oo++) {
      const int oc = ogu * 8 + oo;
      const float sc = dy_g[oc] * rsqrtf(dy_v[oc] + EPSV);
      out[((size_t)(b * 64 + oc)) * 4096 + h * 64 + w] =
          (facc[oo] - dy_m[oc]) * sc + dy_b[oc];
    }
  }
}

// ---------------------------------------------------------------------------
extern "C" void kernel_launch(void* const* d_in, const int* in_sizes, int n_in,
                              void* d_out, int out_size, void* d_ws, size_t ws_size,
                              hipStream_t stream)
{
  const float* x      = (const float*)d_in[0];
  const float* wq_w   = (const float*)d_in[1];
  const float* wq_g   = (const float*)d_in[2];
  const float* wq_b   = (const float*)d_in[3];
  const float* wq_m   = (const float*)d_in[4];
  const float* wq_v   = (const float*)d_in[5];
  const float* wk_w   = (const float*)d_in[6];
  const float* wk_g   = (const float*)d_in[7];
  const float* wk_b   = (const float*)d_in[8];
  const float* wk_m   = (const float*)d_in[9];
  const float* wk_v   = (const float*)d_in[10];
  const float* proj_w = (const float*)d_in[11];
  const float* proj_b = (const float*)d_in[12];
  const float* rpb1   = (const float*)d_in[13];
  const float* rpb2   = (const float*)d_in[14];
  const float* dy_w   = (const float*)d_in[15];
  const float* dy_g   = (const float*)d_in[16];
  const float* dy_b   = (const float*)d_in[17];
  const float* dy_m   = (const float*)d_in[18];
  const float* dy_v   = (const float*)d_in[19];

  float* ws = (float*)d_ws;

  pool_prep_kernel<<<64, 256, 0, stream>>>(x, wk_w, wk_g, wk_b, wk_m, wk_v,
                                           wq_w, wq_g, wq_b, wq_m, wq_v,
                                           dy_w, ws);
  fold_w_kernel<<<32, 256, 0, stream>>>(proj_w, ws, ws + OFF_W);
  contmix_main<<<512, 512, 0, stream>>>(x, proj_b, rpb1, rpb2,
                                        dy_g, dy_b, dy_m, dy_v,
                                        ws, (float*)d_out);
}

// Round 7
// 173.086 us; speedup vs baseline: 1.0974x; 1.0466x over previous
//
#include <hip/hip_runtime.h>

#define EPSV 1e-5f

// Workspace layout (floats):
//   kbuf @ 0     : [b][g][c][l]  8*4*8*49 = 12544
//   W    @ 12544 : [b][g][o<74][c<8]      = 18944   (W = proj_w @ k^T)
//   wq2  @ 31488 : [i][o] 32*32 (BN+scale folded)   = 1024
//   q0   @ 32512 : [o] 32  (folded BN bias * 0.25)  = 32
//   dyT  @ 32544 : [i][o] 64*64                      = 4096
#define OFF_W    12544
#define OFF_WQ2  31488
#define OFF_Q0   32512
#define OFF_DYT  32544

typedef float f4u __attribute__((ext_vector_type(4), aligned(4)));

// ---------------------------------------------------------------------------
// Merged: blocks 0..55 = pool kctx->7x7 + wk conv + BN (kbuf [b][g][c][l]);
// blocks 56..63 = weight prep (wq2/q0 folded BN, dyT transpose).
// ---------------------------------------------------------------------------
__global__ __launch_bounds__(256) void pool_prep_kernel(
    const float* __restrict__ x,
    const float* __restrict__ wk_w, const float* __restrict__ wk_g,
    const float* __restrict__ wk_b, const float* __restrict__ wk_m,
    const float* __restrict__ wk_v,
    const float* __restrict__ wq_w, const float* __restrict__ wq_g,
    const float* __restrict__ wq_b, const float* __restrict__ wq_m,
    const float* __restrict__ wq_v,
    const float* __restrict__ dy_w,
    float* __restrict__ ws)
{
  __shared__ float s_tmp[32 * 64];
  __shared__ float s_kp[32 * 7];
  const int tid = threadIdx.x;

  if (blockIdx.x >= 56) {
    const int t = (blockIdx.x - 56) * 256 + tid;  // 0..2047
    for (int idx = t; idx < 1056; idx += 2048) {
      if (idx < 1024) {
        const int i = idx >> 5, o = idx & 31;
        const float s = wq_g[o] * rsqrtf(wq_v[o] + EPSV);
        ws[OFF_WQ2 + idx] = 0.25f * s * wq_w[o * 32 + i];
      } else {
        const int o = idx - 1024;
        const float s = wq_g[o] * rsqrtf(wq_v[o] + EPSV);
        ws[OFF_Q0 + o] = 0.25f * (wq_b[o] - wq_m[o] * s);
      }
    }
    for (int idx = t; idx < 4096; idx += 2048) {
      const int i = idx >> 6, o = idx & 63;
      ws[OFF_DYT + idx] = dy_w[o * 64 + i];
    }
    return;
  }

  const int b = blockIdx.x / 7;
  const int p = blockIdx.x % 7;
  const int sh = (p * 64) / 7, eh = ((p + 1) * 64 + 6) / 7;
  const float invH = 1.0f / (float)(eh - sh);
  for (int idx = tid; idx < 2048; idx += 256) {
    const int c = idx >> 6, ww = idx & 63;
    const float* xp = x + ((size_t)(b * 64 + 32 + c)) * 4096 + ww;
    float s = 0.f;
    for (int hh = sh; hh < eh; ++hh) s += xp[hh * 64];
    s_tmp[idx] = s * invH;
  }
  __syncthreads();
  if (tid < 224) {
    const int c = tid / 7, q = tid % 7;
    const int sw = (q * 64) / 7, ew = ((q + 1) * 64 + 6) / 7;
    float s = 0.f;
    for (int ww = sw; ww < ew; ++ww) s += s_tmp[c * 64 + ww];
    s_kp[c * 7 + q] = s / (float)(ew - sw);
  }
  __syncthreads();
  if (tid < 224) {
    const int o = tid / 7, q = tid % 7;
    float s = 0.f;
#pragma unroll
    for (int i = 0; i < 32; i++) s += wk_w[o * 32 + i] * s_kp[i * 7 + q];
    const float sc = wk_g[o] * rsqrtf(wk_v[o] + EPSV);
    const int g = o >> 3, c = o & 7, l = p * 7 + q;
    ws[(((size_t)b * 4 + g) * 8 + c) * 49 + l] = (s - wk_m[o]) * sc + wk_b[o];
  }
}

// ---------------------------------------------------------------------------
// W[bg][o][c] = sum_l proj_w[o][l] * k[bg][c][l].
// ---------------------------------------------------------------------------
__global__ __launch_bounds__(256) void fold_w_kernel(
    const float* __restrict__ proj_w, const float* __restrict__ ws_in,
    float* __restrict__ Wout)
{
  const int bg = blockIdx.x;
  const int tid = threadIdx.x;
  __shared__ float s_k[392];
  for (int i = tid; i < 392; i += 256) s_k[i] = ws_in[(size_t)bg * 392 + i];
  __syncthreads();
  for (int idx = tid; idx < 592; idx += 256) {
    const int o = idx >> 3, c = idx & 7;
    float s = 0.f;
#pragma unroll
    for (int l = 0; l < 49; l++) s += proj_w[o * 49 + l] * s_k[c * 49 + l];
    Wout[(size_t)bg * 592 + idx] = s;
  }
}

// ---------------------------------------------------------------------------
// Fused main — R4 structure exactly (known non-spilling), with folded wq BN
// and no-max softmax. Block = 512 = 2 branches x 4 heads x 64 cols, one row.
// ---------------------------------------------------------------------------
__global__ __launch_bounds__(512, 3) void contmix_main(
    const float* __restrict__ x,
    const float* __restrict__ proj_b,
    const float* __restrict__ rpb1, const float* __restrict__ rpb2,
    const float* __restrict__ dy_g, const float* __restrict__ dy_b,
    const float* __restrict__ dy_m, const float* __restrict__ dy_v,
    const float* __restrict__ ws,
    float* __restrict__ out)
{
  __shared__ float s_rpb1[4 * 81];
  __shared__ float s_rpb2[4 * 169];
  __shared__ float s_val[64 * 64];  // [ch][w]

  const int bx = blockIdx.x;
  const int b = bx >> 6;
  const int h = bx & 63;
  const int tid = threadIdx.x;
  const int w = tid & 63;
  const int bru = __builtin_amdgcn_readfirstlane(tid >> 8);
  const int gu  = __builtin_amdgcn_readfirstlane((tid >> 6) & 3);

  for (int i = tid; i < 324; i += 512) s_rpb1[i] = rpb1[i];
  for (int i = tid; i < 676; i += 512) s_rpb2[i] = rpb2[i];
  __syncthreads();

  const float* xb = x + (size_t)b * 64 * 4096;

  // ---- q8 (BN+scale pre-folded into wq2/q0) ----
  float q8[8];
  {
    const float* q0 = ws + OFF_Q0 + gu * 8;
#pragma unroll
    for (int o = 0; o < 8; o++) q8[o] = q0[o];
    const float* wq2 = ws + OFF_WQ2 + gu * 8;
#pragma unroll
    for (int i = 0; i < 32; i++) {
      const float xv = xb[i * 4096 + h * 64 + w];
#pragma unroll
      for (int o = 0; o < 8; o++) q8[o] += wq2[i * 32 + o] * xv;
    }
  }

  const float* Wr = ws + OFF_W + (size_t)(b * 4 + gu) * 592;  // uniform
  const int ph = 63 - h, pw = 63 - w;

  if (bru == 0) {
    // ===== attn1 (5x5) =====
    const int bih5 = ph - min(max(ph - 2, 0), 59);
    const int biw5 = pw - min(max(pw - 2, 0), 59);
    const int si5 = min(max(h - 2, 0), 59), sj5 = min(max(w - 2, 0), 59);
    float l1[25];
#pragma unroll
    for (int o = 0; o < 25; o++) {
      const float* wo = Wr + o * 8;
      float s = proj_b[o];
#pragma unroll
      for (int c = 0; c < 8; c++) s += wo[c] * q8[c];
      l1[o] = s;
    }
    const float* rp1 = s_rpb1 + gu * 81 + bih5 * 9 + biw5;
#pragma unroll
    for (int ki = 0; ki < 5; ki++)
#pragma unroll
      for (int kj = 0; kj < 5; kj++) l1[ki * 5 + kj] += rp1[ki * 9 + kj];

    float p0 = 0.f, p1 = 0.f, p2 = 0.f, p3 = 0.f;
#pragma unroll
    for (int o = 0; o < 25; o++) {
      const float e = __expf(l1[o]);
      l1[o] = e;
      if ((o & 3) == 0) p0 += e;
      else if ((o & 3) == 1) p1 += e;
      else if ((o & 3) == 2) p2 += e;
      else p3 += e;
    }
    const float inv = 1.f / ((p0 + p1) + (p2 + p3));

    float acc[8];
#pragma unroll
    for (int c = 0; c < 8; c++) acc[c] = 0.f;
    const float* vb = xb + gu * 8 * 4096;
#pragma unroll
    for (int i = 0; i < 5; i++) {
      const float a0 = l1[i * 5 + 0], a1 = l1[i * 5 + 1], a2 = l1[i * 5 + 2];
      const float a3 = l1[i * 5 + 3], a4 = l1[i * 5 + 4];
      const float* vr0 = vb + (si5 + i) * 64 + sj5;
#pragma unroll
      for (int c = 0; c < 8; c++) {
        const float* vr = vr0 + c * 4096;
        const f4u f = *(const f4u*)vr;
        const float v4 = vr[4];
        acc[c] += a0 * f.x + a1 * f.y + a2 * f.z + a3 * f.w + a4 * v4;
      }
    }
#pragma unroll
    for (int c = 0; c < 8; c++) s_val[(gu * 8 + c) * 64 + w] = acc[c] * inv;
  } else {
    // ===== attn2 (7x7) =====
    const int bih7 = ph - min(max(ph - 3, 0), 57);
    const int biw7 = pw - min(max(pw - 3, 0), 57);
    const int si7 = min(max(h - 3, 0), 57), sj7 = min(max(w - 3, 0), 57);
    float l2[49];
#pragma unroll
    for (int o = 0; o < 49; o++) {
      const float* wo = Wr + (25 + o) * 8;
      float s = proj_b[25 + o];
#pragma unroll
      for (int c = 0; c < 8; c++) s += wo[c] * q8[c];
      l2[o] = s;
    }
    const float* rp2 = s_rpb2 + gu * 169 + bih7 * 13 + biw7;
#pragma unroll
    for (int ki = 0; ki < 7; ki++)
#pragma unroll
      for (int kj = 0; kj < 7; kj++) l2[ki * 7 + kj] += rp2[ki * 13 + kj];

    float p0 = 0.f, p1 = 0.f, p2 = 0.f, p3 = 0.f;
#pragma unroll
    for (int o = 0; o < 49; o++) {
      const float e = __expf(l2[o]);
      l2[o] = e;
      if ((o & 3) == 0) p0 += e;
      else if ((o & 3) == 1) p1 += e;
      else if ((o & 3) == 2) p2 += e;
      else p3 += e;
    }
    const float inv = 1.f / ((p0 + p1) + (p2 + p3));

    float acc[8];
#pragma unroll
    for (int c = 0; c < 8; c++) acc[c] = 0.f;
    const float* vb = xb + (32 + gu * 8) * 4096;
#pragma unroll
    for (int i = 0; i < 7; i++) {
      const float a0 = l2[i * 7 + 0], a1 = l2[i * 7 + 1], a2 = l2[i * 7 + 2];
      const float a3 = l2[i * 7 + 3], a4 = l2[i * 7 + 4], a5 = l2[i * 7 + 5];
      const float a6 = l2[i * 7 + 6];
      const float* vr0 = vb + (si7 + i) * 64 + sj7;
#pragma unroll
      for (int c = 0; c < 8; c++) {
        const float* vr = vr0 + c * 4096;
        const f4u fa = *(const f4u*)vr;
        const f4u fb = *(const f4u*)(vr + 3);
        acc[c] += a0 * fa.x + a1 * fa.y + a2 * fa.z + a3 * fa.w +
                  a4 * fb.y + a5 * fb.z + a6 * fb.w;
      }
    }
#pragma unroll
    for (int c = 0; c < 8; c++) s_val[(32 + gu * 8 + c) * 64 + w] = acc[c] * inv;
  }

  __syncthreads();

  // ===== fused final conv1x1 (64->64) + BN =====
  {
    const int ogu = __builtin_amdgcn_readfirstlane(tid >> 6);  // 0..7
    float facc[8];
#pragma unroll
    for (int oo = 0; oo < 8; oo++) facc[oo] = 0.f;
    const float* dyt = ws + OFF_DYT + ogu * 8;
#pragma unroll
    for (int i = 0; i < 64; i++) {
      const float v = s_val[i * 64 + w];
#pragma unroll
      for (int oo = 0; oo < 8; oo++) facc[oo] += dyt[i * 64 + oo] * v;
    }
#pragma unroll
    for (int oo = 0; oo < 8; oo++) {
      const int oc = ogu * 8 + oo;
      const float sc = dy_g[oc] * rsqrtf(dy_v[oc] + EPSV);
      out[((size_t)(b * 64 + oc)) * 4096 + h * 64 + w] =
          (facc[oo] - dy_m[oc]) * sc + dy_b[oc];
    }
  }
}

// ---------------------------------------------------------------------------
extern "C" void kernel_launch(void* const* d_in, const int* in_sizes, int n_in,
                              void* d_out, int out_size, void* d_ws, size_t ws_size,
                              hipStream_t stream)
{
  const float* x      = (const float*)d_in[0];
  const float* wq_w   = (const float*)d_in[1];
  const float* wq_g   = (const float*)d_in[2];
  const float* wq_b   = (const float*)d_in[3];
  const float* wq_m   = (const float*)d_in[4];
  const float* wq_v   = (const float*)d_in[5];
  const float* wk_w   = (const float*)d_in[6];
  const float* wk_g   = (const float*)d_in[7];
  const float* wk_b   = (const float*)d_in[8];
  const float* wk_m   = (const float*)d_in[9];
  const float* wk_v   = (const float*)d_in[10];
  const float* proj_w = (const float*)d_in[11];
  const float* proj_b = (const float*)d_in[12];
  const float* rpb1   = (const float*)d_in[13];
  const float* rpb2   = (const float*)d_in[14];
  const float* dy_w   = (const float*)d_in[15];
  const float* dy_g   = (const float*)d_in[16];
  const float* dy_b   = (const float*)d_in[17];
  const float* dy_m   = (const float*)d_in[18];
  const float* dy_v   = (const float*)d_in[19];

  float* ws = (float*)d_ws;

  pool_prep_kernel<<<64, 256, 0, stream>>>(x, wk_w, wk_g, wk_b, wk_m, wk_v,
                                           wq_w, wq_g, wq_b, wq_m, wq_v,
                                           dy_w, ws);
  fold_w_kernel<<<32, 256, 0, stream>>>(proj_w, ws, ws + OFF_W);
  contmix_main<<<512, 512, 0, stream>>>(x, proj_b, rpb1, rpb2,
                                        dy_g, dy_b, dy_m, dy_v,
                                        ws, (float*)d_out);
}